// Round 10
// baseline (189.768 us; speedup 1.0000x reference)
//
#include <hip/hip_runtime.h>

typedef __bf16 bf16x8 __attribute__((ext_vector_type(8)));
typedef unsigned short u16x8 __attribute__((ext_vector_type(8)));
typedef u16x8 u16x8_a __attribute__((may_alias));
typedef unsigned short u16x4 __attribute__((ext_vector_type(4)));
typedef u16x4 u16x4_a __attribute__((may_alias));
typedef unsigned int u32x4 __attribute__((ext_vector_type(4)));
typedef u32x4 u32x4_a __attribute__((may_alias));
typedef float f32x4 __attribute__((ext_vector_type(4)));

#define LOG2E 1.4426950408889634f
#define NEGV  -10000.0f

__device__ __forceinline__ float bf2f(unsigned short u){
  union{unsigned int i; float f;} x; x.i = ((unsigned int)u)<<16; return x.f;
}
__device__ __forceinline__ unsigned short f2bf(float f){
  union{float f; unsigned int i;} x; x.f=f;
  unsigned int i = x.i;
  return (unsigned short)((i + 0x7FFFu + ((i>>16)&1u)) >> 16);
}
__device__ __forceinline__ bf16x8 ldb(const unsigned short* p){
  return __builtin_bit_cast(bf16x8, *(const u16x8_a*)p);
}

// ---------------- prep: z<6 -> weight transpose+cast; z==6 -> cast inputs to Ab ----------------
__global__ __launch_bounds__(256) void prep(
    const float* __restrict__ w0, const float* __restrict__ w1,
    const float* __restrict__ w2, const float* __restrict__ w3,
    const float* __restrict__ w4, const float* __restrict__ w5,
    const float* __restrict__ word, const float* __restrict__ ent,
    unsigned short* __restrict__ outT, unsigned short* __restrict__ Ab)
{
  int tx = threadIdx.x, ty = threadIdx.y;
  if (blockIdx.z == 6){
    // cast word (393216 f4) ++ ent (24576 f4) -> Ab bf16
    int blk = blockIdx.y*24 + blockIdx.x;
    int gtid = blk*256 + ty*32 + tx;
    for (int idx = gtid; idx < 417792; idx += 147456){
      float4 v = (idx < 393216) ? ((const float4*)word)[idx]
                                : ((const float4*)ent)[idx - 393216];
      u16x4 r; r[0]=f2bf(v.x); r[1]=f2bf(v.y); r[2]=f2bf(v.z); r[3]=f2bf(v.w);
      *(u16x4_a*)(Ab + (size_t)idx*4) = r;
    }
    return;
  }
  const float* src;
  switch (blockIdx.z){
    case 0: src = w0; break; case 1: src = w1; break; case 2: src = w2; break;
    case 3: src = w3; break; case 4: src = w4; break; default: src = w5; break;
  }
  unsigned short* dst = outT + (size_t)blockIdx.z * 589824;
  __shared__ float tile[32][33];
  int x0 = blockIdx.x*32, y0 = blockIdx.y*32;
  #pragma unroll
  for (int i=0;i<32;i+=8) tile[ty+i][tx] = src[(size_t)(y0+ty+i)*768 + x0+tx];
  __syncthreads();
  #pragma unroll
  for (int i=0;i<32;i+=8) dst[(size_t)(x0+ty+i)*768 + y0+tx] = f2bf(tile[tx][ty+i]);
}

// ---------------- V transpose: VbT[d][key] = Vb[key][d] ----------------
__global__ __launch_bounds__(256) void transpose_v(
    const unsigned short* __restrict__ Vb, unsigned short* __restrict__ VbT)
{
  __shared__ unsigned short t[32][33];
  int tx = threadIdx.x, ty = threadIdx.y;
  int x0 = blockIdx.x*32;   // key
  int y0 = blockIdx.y*32;   // dim
  #pragma unroll
  for (int i=0;i<32;i+=8) t[ty+i][tx] = Vb[(size_t)(x0+ty+i)*768 + y0+tx];
  __syncthreads();
  #pragma unroll
  for (int i=0;i<32;i+=8) VbT[(size_t)(y0+ty+i)*2176 + x0+tx] = t[tx][ty+i];
}

// ---------------- projection GEMM, 64x128 tiles, all-bf16 staging ----------------
// m-tile map: g0 K: 0..33 | g1 V: 34..67 | g2 Q: 68..99 | g3 W2E: 100..131
//             g4 E2W: 132..133 | g5 E2E: 134..135   (x6 n-tiles)
__global__ __launch_bounds__(256) void gemm2(
    const unsigned short* __restrict__ Ab, const unsigned short* __restrict__ wT,
    const float* __restrict__ bK, const float* __restrict__ bV,
    const float* __restrict__ bQ, const float* __restrict__ bWE,
    const float* __restrict__ bEW, const float* __restrict__ bEE,
    unsigned short* __restrict__ oK, unsigned short* __restrict__ oV,
    unsigned short* __restrict__ oQ, unsigned short* __restrict__ oWE,
    unsigned short* __restrict__ oEW, unsigned short* __restrict__ oEE)
{
  int mt = blockIdx.x, ntile = blockIdx.y;
  int g, m0, mo;
  if      (mt < 34){ g=0; mo=mt;      m0=mo*64; }
  else if (mt < 68){ g=1; mo=mt-34;   m0=mo*64; }
  else if (mt <100){ g=2; mo=mt-68;   m0=mo*64; }
  else if (mt <132){ g=3; mo=mt-100;  m0=mo*64; }
  else if (mt <134){ g=4; mo=mt-132;  m0=2048+mo*64; }
  else             { g=5; mo=mt-134;  m0=2048+mo*64; }
  const unsigned short* A = Ab + (size_t)m0*768;
  const unsigned short* B = wT + (size_t)g*589824;
  const float* bias; unsigned short* out;
  switch (g){
    case 0: bias=bK;  out=oK  + (size_t)m0*768;    break;
    case 1: bias=bV;  out=oV  + (size_t)m0*768;    break;
    case 2: bias=bQ;  out=oQ  + (size_t)m0*768;    break;
    case 3: bias=bWE; out=oWE + (size_t)m0*768;    break;
    case 4: bias=bEW; out=oEW + (size_t)(mo*64)*768; break;
    default:bias=bEE; out=oEE + (size_t)(mo*64)*768; break;
  }
  int n0 = ntile*128;

  __shared__ __align__(16) unsigned short a_s[64*32];
  __shared__ __align__(16) unsigned short b_s[128*32];

  int tid  = threadIdx.x;
  int w    = tid>>6, lane = tid&63, quad = lane>>4, lr = lane&15;
  int wm   = (w&1)*32, wn = (w>>1)*64;

  f32x4 acc[2][4];
  #pragma unroll
  for (int i=0;i<2;i++) for (int j=0;j<4;j++) for (int r=0;r<4;r++) acc[i][j][r]=0.f;

  int ar = tid>>2, ak = (tid&3)*8;      // A: 64 rows x 32
  int br = tid>>1, bk = (tid&1)*16;     // B: 128 rows x 32
  const unsigned short* Arow = A + (size_t)ar*768 + ak;
  const unsigned short* Brow = B + (size_t)(n0+br)*768 + bk;

  for (int k0=0; k0<768; k0+=32){
    u16x8 av  = *(const u16x8_a*)(Arow + k0);
    u16x8 bv0 = *(const u16x8_a*)(Brow + k0);
    u16x8 bv1 = *(const u16x8_a*)(Brow + k0 + 8);
    __syncthreads();
    *(u16x8_a*)(a_s + ar*32 + ak)      = av;
    *(u16x8_a*)(b_s + br*32 + bk)      = bv0;
    *(u16x8_a*)(b_s + br*32 + bk + 8)  = bv1;
    __syncthreads();
    bf16x8 af[2], bfr[4];
    #pragma unroll
    for (int i=0;i<2;i++) af[i]  = ldb(a_s + (wm+i*16+lr)*32 + quad*8);
    #pragma unroll
    for (int j=0;j<4;j++) bfr[j] = ldb(b_s + (wn+j*16+lr)*32 + quad*8);
    #pragma unroll
    for (int i=0;i<2;i++)
      #pragma unroll
      for (int j=0;j<4;j++)
        acc[i][j] = __builtin_amdgcn_mfma_f32_16x16x32_bf16(af[i], bfr[j], acc[i][j], 0,0,0);
  }
  #pragma unroll
  for (int j=0;j<4;j++){
    int col = n0 + wn + j*16 + lr;
    float bb = bias[col];
    #pragma unroll
    for (int i=0;i<2;i++){
      int rowb = wm + i*16 + quad*4;
      #pragma unroll
      for (int r=0;r<4;r++)
        out[(size_t)(rowb+r)*768 + col] = f2bf(acc[i][j][r] + bb);
    }
  }
}

// ---------------- split-key MFMA flash attention: 16 q-rows/block, 4-way key split ----
// blocks 0..127: word; 128..135: entity. grid.y = head.
__global__ __launch_bounds__(256) void attn4(
  const unsigned short* __restrict__ Kb,  const unsigned short* __restrict__ VbT,
  const unsigned short* __restrict__ Qw,  const unsigned short* __restrict__ Qwe,
  const unsigned short* __restrict__ Qew, const unsigned short* __restrict__ Qee,
  const float* __restrict__ am,
  float* __restrict__ outw, float* __restrict__ oute)
{
  int bx = blockIdx.x, h = blockIdx.y;
  int tid = threadIdx.x, w = tid>>6, lane = tid&63, quad = lane>>4, lr = lane&15;
  bool isword = bx < 128;
  int qrb = isword ? bx*16 : (bx-128)*16;
  const unsigned short* Qa = isword ? Qw  : Qew;
  const unsigned short* Qb = isword ? Qwe : Qee;
  float* outp = isword ? outw : oute;

  __shared__ __align__(16) unsigned int p32[4][16*24];  // packed P per wave
  __shared__ float mrg[4][64][24];                      // merge buffer

  const unsigned short* qr = Qa + (size_t)(qrb+lr)*768 + h*64 + quad*8;
  bf16x8 qa0 = ldb(qr), qa1 = ldb(qr + 32);
  qr = Qb + (size_t)(qrb+lr)*768 + h*64 + quad*8;
  bf16x8 qb0 = ldb(qr), qb1 = ldb(qr + 32);

  float m_r[4], l_r[4];
  f32x4 o[4];
  #pragma unroll
  for (int r=0;r<4;r++){ m_r[r] = -1e30f; l_r[r] = 0.f; }
  #pragma unroll
  for (int n2=0;n2<4;n2++) for (int r=0;r<4;r++) o[n2][r] = 0.f;

  int lo, nw;
  if (isword){
    lo = qrb - 256; if (lo < 0) lo = 0; lo &= ~31;
    int hi = qrb + 16 + 256; if (hi > 2048) hi = 2048; hi = (hi + 31) & ~31;
    nw = (hi - lo) >> 5;
  } else { lo = 0; nw = 64; }
  int nc = nw + 4;

  for (int c = w; c < nc; c += 4){
    bool entp = c >= nw;
    int j0 = entp ? (2048 + (c-nw)*32) : (lo + c*32);

    const unsigned short* kp = Kb + (size_t)(j0+lr)*768 + h*64 + quad*8;
    bf16x8 k00 = ldb(kp),          k01 = ldb(kp + 32);
    bf16x8 k10 = ldb(kp + 16*768), k11 = ldb(kp + 16*768 + 32);
    const unsigned short* vp = VbT + (size_t)(h*64 + lr)*2176 + j0 + quad*8;
    bf16x8 v0 = ldb(vp), v1 = ldb(vp + 16*2176), v2 = ldb(vp + 32*2176), v3 = ldb(vp + 48*2176);

    bf16x8 qf0 = entp ? qb0 : qa0;
    bf16x8 qf1 = entp ? qb1 : qa1;
    f32x4 s[2];
    {
      f32x4 z0 = {0.f,0.f,0.f,0.f}, z1 = {0.f,0.f,0.f,0.f};
      z0 = __builtin_amdgcn_mfma_f32_16x16x32_bf16(qf0, k00, z0, 0,0,0);
      z0 = __builtin_amdgcn_mfma_f32_16x16x32_bf16(qf1, k01, z0, 0,0,0);
      z1 = __builtin_amdgcn_mfma_f32_16x16x32_bf16(qf0, k10, z1, 0,0,0);
      z1 = __builtin_amdgcn_mfma_f32_16x16x32_bf16(qf1, k11, z1, 0,0,0);
      s[0] = z0; s[1] = z1;
    }

    float sc[2][4];
    bool wband = isword && !entp;
    #pragma unroll
    for (int t=0;t<2;t++){
      int j = j0 + t*16 + lr;
      float amj  = am[j];
      float addl = amj * LOG2E;
      #pragma unroll
      for (int r=0;r<4;r++){
        float sv = s[t][r];
        if (wband){
          sv += (amj != 0.f) ? NEGV : 0.f;                              // float_mask pre-add
          int i = qrb + quad*4 + r;
          bool ok = ((unsigned)(i - j + 256) <= 512u) && (sv != 0.f);   // band & !=0 quirk
          sv = ok ? sv : NEGV;
        }
        sc[t][r] = sv * (LOG2E*0.125f) + addl;
      }
    }

    #pragma unroll
    for (int r=0;r<4;r++){
      float mx = fmaxf(sc[0][r], sc[1][r]);
      mx = fmaxf(mx, __shfl_xor(mx, 1));
      mx = fmaxf(mx, __shfl_xor(mx, 2));
      mx = fmaxf(mx, __shfl_xor(mx, 4));
      mx = fmaxf(mx, __shfl_xor(mx, 8));
      float mn = fmaxf(m_r[r], mx);
      float alpha = exp2f(m_r[r] - mn);
      m_r[r] = mn;
      float p0 = exp2f(sc[0][r]-mn), p1 = exp2f(sc[1][r]-mn);
      unsigned short pb0 = f2bf(p0), pb1 = f2bf(p1);
      float rs = bf2f(pb0) + bf2f(pb1);
      rs += __shfl_xor(rs,1); rs += __shfl_xor(rs,2);
      rs += __shfl_xor(rs,4); rs += __shfl_xor(rs,8);
      l_r[r] = l_r[r]*alpha + rs;
      p32[w][(quad*4+r)*24 + lr] = (unsigned int)pb0 | ((unsigned int)pb1 << 16);
      #pragma unroll
      for (int n2=0;n2<4;n2++) o[n2][r] *= alpha;
    }

    // P (C-layout) -> A-frag, wave-local LDS round-trip
    const unsigned int* pbp = &p32[w][lr*24 + (quad&1)*8];
    u32x4 ra = *(const u32x4_a*)pbp;
    u32x4 rb = *(const u32x4_a*)(pbp + 4);
    unsigned int pf32[4];
    if (quad < 2){
      pf32[0] = (ra[0]&0xFFFFu) | (ra[1]<<16);
      pf32[1] = (ra[2]&0xFFFFu) | (ra[3]<<16);
      pf32[2] = (rb[0]&0xFFFFu) | (rb[1]<<16);
      pf32[3] = (rb[2]&0xFFFFu) | (rb[3]<<16);
    } else {
      pf32[0] = (ra[0]>>16) | (ra[1]&0xFFFF0000u);
      pf32[1] = (ra[2]>>16) | (ra[3]&0xFFFF0000u);
      pf32[2] = (rb[0]>>16) | (rb[1]&0xFFFF0000u);
      pf32[3] = (rb[2]>>16) | (rb[3]&0xFFFF0000u);
    }
    u32x4 pfv = {pf32[0], pf32[1], pf32[2], pf32[3]};
    bf16x8 pf = __builtin_bit_cast(bf16x8, pfv);

    o[0] = __builtin_amdgcn_mfma_f32_16x16x32_bf16(pf, v0, o[0], 0,0,0);
    o[1] = __builtin_amdgcn_mfma_f32_16x16x32_bf16(pf, v1, o[1], 0,0,0);
    o[2] = __builtin_amdgcn_mfma_f32_16x16x32_bf16(pf, v2, o[2], 0,0,0);
    o[3] = __builtin_amdgcn_mfma_f32_16x16x32_bf16(pf, v3, o[3], 0,0,0);
  }

  // ---- cross-wave merge (single barrier) ----
  {
    float* my = &mrg[w][lane][0];
    #pragma unroll
    for (int r=0;r<4;r++){ my[r] = m_r[r]; my[4+r] = l_r[r]; }
    #pragma unroll
    for (int n2=0;n2<4;n2++)
      #pragma unroll
      for (int r=0;r<4;r++) my[8+n2*4+r] = o[n2][r];
  }
  __syncthreads();
  if (w == 0){
    for (int p=1; p<4; p++){
      const float* pr = &mrg[p][lane][0];
      #pragma unroll
      for (int r=0;r<4;r++){
        float m2 = pr[r], l2 = pr[4+r];
        float M  = fmaxf(m_r[r], m2);
        float e1 = exp2f(m_r[r]-M), e2 = exp2f(m2-M);
        m_r[r] = M;
        l_r[r] = l_r[r]*e1 + l2*e2;
        #pragma unroll
        for (int n2=0;n2<4;n2++)
          o[n2][r] = o[n2][r]*e1 + pr[8+n2*4+r]*e2;
      }
    }
    #pragma unroll
    for (int n2=0;n2<4;n2++)
      #pragma unroll
      for (int r=0;r<4;r++){
        int row = qrb + quad*4 + r;
        outp[(size_t)row*768 + h*64 + n2*16 + lr] = o[n2][r] / l_r[r];
      }
  }
}

extern "C" void kernel_launch(void* const* d_in, const int* in_sizes, int n_in,
                              void* d_out, int out_size, void* d_ws, size_t ws_size,
                              hipStream_t stream) {
  const float* word  = (const float*)d_in[0];
  const float* ent   = (const float*)d_in[1];
  const float* am    = (const float*)d_in[2];
  const float* q_w   = (const float*)d_in[3];
  const float* q_b   = (const float*)d_in[4];
  const float* k_w   = (const float*)d_in[5];
  const float* k_b   = (const float*)d_in[6];
  const float* v_w   = (const float*)d_in[7];
  const float* v_b   = (const float*)d_in[8];
  const float* w2e_w = (const float*)d_in[9];
  const float* w2e_b = (const float*)d_in[10];
  const float* e2w_w = (const float*)d_in[11];
  const float* e2w_b = (const float*)d_in[12];
  const float* e2e_w = (const float*)d_in[13];
  const float* e2e_b = (const float*)d_in[14];

  unsigned short* ws  = (unsigned short*)d_ws;
  unsigned short* wT  = ws;                       // 6*768*768 bf16
  unsigned short* Ab  = wT  + (size_t)6*589824;   // 2176*768 (bf16 word||ent)
  unsigned short* Kb  = Ab  + (size_t)2176*768;
  unsigned short* Vb  = Kb  + (size_t)2176*768;
  unsigned short* Qw  = Vb  + (size_t)2176*768;   // 2048*768
  unsigned short* Qwe = Qw  + (size_t)2048*768;
  unsigned short* Qew = Qwe + (size_t)2048*768;   // 128*768
  unsigned short* Qee = Qew + (size_t)128*768;
  unsigned short* VbT = Qee + (size_t)128*768;    // 768*2176

  float* outw = (float*)d_out;                    // fp32 output
  float* oute = outw + (size_t)2048*768;

  hipLaunchKernelGGL(prep, dim3(24,24,7), dim3(32,8), 0, stream,
                     k_w, v_w, q_w, w2e_w, e2w_w, e2e_w, word, ent, wT, Ab);
  hipLaunchKernelGGL(gemm2, dim3(136,6), dim3(256), 0, stream,
                     Ab, wT, k_b, v_b, q_b, w2e_b, e2w_b, e2e_b,
                     Kb, Vb, Qw, Qwe, Qew, Qee);
  hipLaunchKernelGGL(transpose_v, dim3(68,24), dim3(32,8), 0, stream, Vb, VbT);
  hipLaunchKernelGGL(attn4, dim3(136,12), dim3(256), 0, stream,
                     Kb, VbT, Qw, Qwe, Qew, Qee, am, outw, oute);
}

// Round 11
// 184.651 us; speedup vs baseline: 1.0277x; 1.0277x over previous
//
#include <hip/hip_runtime.h>

typedef __bf16 bf16x8 __attribute__((ext_vector_type(8)));
typedef unsigned short u16x8 __attribute__((ext_vector_type(8)));
typedef u16x8 u16x8_a __attribute__((may_alias));
typedef unsigned short u16x4 __attribute__((ext_vector_type(4)));
typedef u16x4 u16x4_a __attribute__((may_alias));
typedef unsigned int u32x4 __attribute__((ext_vector_type(4)));
typedef u32x4 u32x4_a __attribute__((may_alias));
typedef float f32x4 __attribute__((ext_vector_type(4)));

#define LOG2E 1.4426950408889634f
#define NEGV  -10000.0f

__device__ __forceinline__ float bf2f(unsigned short u){
  union{unsigned int i; float f;} x; x.i = ((unsigned int)u)<<16; return x.f;
}
__device__ __forceinline__ unsigned short f2bf(float f){
  union{float f; unsigned int i;} x; x.f=f;
  unsigned int i = x.i;
  return (unsigned short)((i + 0x7FFFu + ((i>>16)&1u)) >> 16);
}
__device__ __forceinline__ bf16x8 ldb(const unsigned short* p){
  return __builtin_bit_cast(bf16x8, *(const u16x8_a*)p);
}

// ---------------- prep: z<6 -> weight transpose+cast; z==6 -> cast inputs to Ab ----------------
__global__ __launch_bounds__(256) void prep(
    const float* __restrict__ w0, const float* __restrict__ w1,
    const float* __restrict__ w2, const float* __restrict__ w3,
    const float* __restrict__ w4, const float* __restrict__ w5,
    const float* __restrict__ word, const float* __restrict__ ent,
    unsigned short* __restrict__ outT, unsigned short* __restrict__ Ab)
{
  int tx = threadIdx.x, ty = threadIdx.y;
  if (blockIdx.z == 6){
    int blk = blockIdx.y*24 + blockIdx.x;
    int gtid = blk*256 + ty*32 + tx;
    for (int idx = gtid; idx < 417792; idx += 147456){
      float4 v = (idx < 393216) ? ((const float4*)word)[idx]
                                : ((const float4*)ent)[idx - 393216];
      u16x4 r; r[0]=f2bf(v.x); r[1]=f2bf(v.y); r[2]=f2bf(v.z); r[3]=f2bf(v.w);
      *(u16x4_a*)(Ab + (size_t)idx*4) = r;
    }
    return;
  }
  const float* src;
  switch (blockIdx.z){
    case 0: src = w0; break; case 1: src = w1; break; case 2: src = w2; break;
    case 3: src = w3; break; case 4: src = w4; break; default: src = w5; break;
  }
  unsigned short* dst = outT + (size_t)blockIdx.z * 589824;
  __shared__ float tile[32][33];
  int x0 = blockIdx.x*32, y0 = blockIdx.y*32;
  #pragma unroll
  for (int i=0;i<32;i+=8) tile[ty+i][tx] = src[(size_t)(y0+ty+i)*768 + x0+tx];
  __syncthreads();
  #pragma unroll
  for (int i=0;i<32;i+=8) dst[(size_t)(x0+ty+i)*768 + y0+tx] = f2bf(tile[tx][ty+i]);
}

// ---------------- V transpose: VbT[d][key] = Vb[key][d] ----------------
__global__ __launch_bounds__(256) void transpose_v(
    const unsigned short* __restrict__ Vb, unsigned short* __restrict__ VbT)
{
  __shared__ unsigned short t[32][33];
  int tx = threadIdx.x, ty = threadIdx.y;
  int x0 = blockIdx.x*32;   // key
  int y0 = blockIdx.y*32;   // dim
  #pragma unroll
  for (int i=0;i<32;i+=8) t[ty+i][tx] = Vb[(size_t)(x0+ty+i)*768 + y0+tx];
  __syncthreads();
  #pragma unroll
  for (int i=0;i<32;i+=8) VbT[(size_t)(y0+ty+i)*2176 + x0+tx] = t[tx][ty+i];
}

// ---------------- projection GEMM, 64x128 tiles, all-bf16 staging (unchanged R10) ----------------
__global__ __launch_bounds__(256) void gemm2(
    const unsigned short* __restrict__ Ab, const unsigned short* __restrict__ wT,
    const float* __restrict__ bK, const float* __restrict__ bV,
    const float* __restrict__ bQ, const float* __restrict__ bWE,
    const float* __restrict__ bEW, const float* __restrict__ bEE,
    unsigned short* __restrict__ oK, unsigned short* __restrict__ oV,
    unsigned short* __restrict__ oQ, unsigned short* __restrict__ oWE,
    unsigned short* __restrict__ oEW, unsigned short* __restrict__ oEE)
{
  int mt = blockIdx.x, ntile = blockIdx.y;
  int g, m0, mo;
  if      (mt < 34){ g=0; mo=mt;      m0=mo*64; }
  else if (mt < 68){ g=1; mo=mt-34;   m0=mo*64; }
  else if (mt <100){ g=2; mo=mt-68;   m0=mo*64; }
  else if (mt <132){ g=3; mo=mt-100;  m0=mo*64; }
  else if (mt <134){ g=4; mo=mt-132;  m0=2048+mo*64; }
  else             { g=5; mo=mt-134;  m0=2048+mo*64; }
  const unsigned short* A = Ab + (size_t)m0*768;
  const unsigned short* B = wT + (size_t)g*589824;
  const float* bias; unsigned short* out;
  switch (g){
    case 0: bias=bK;  out=oK  + (size_t)m0*768;    break;
    case 1: bias=bV;  out=oV  + (size_t)m0*768;    break;
    case 2: bias=bQ;  out=oQ  + (size_t)m0*768;    break;
    case 3: bias=bWE; out=oWE + (size_t)m0*768;    break;
    case 4: bias=bEW; out=oEW + (size_t)(mo*64)*768; break;
    default:bias=bEE; out=oEE + (size_t)(mo*64)*768; break;
  }
  int n0 = ntile*128;

  __shared__ __align__(16) unsigned short a_s[64*32];
  __shared__ __align__(16) unsigned short b_s[128*32];

  int tid  = threadIdx.x;
  int w    = tid>>6, lane = tid&63, quad = lane>>4, lr = lane&15;
  int wm   = (w&1)*32, wn = (w>>1)*64;

  f32x4 acc[2][4];
  #pragma unroll
  for (int i=0;i<2;i++) for (int j=0;j<4;j++) for (int r=0;r<4;r++) acc[i][j][r]=0.f;

  int ar = tid>>2, ak = (tid&3)*8;
  int br = tid>>1, bk = (tid&1)*16;
  const unsigned short* Arow = A + (size_t)ar*768 + ak;
  const unsigned short* Brow = B + (size_t)(n0+br)*768 + bk;

  for (int k0=0; k0<768; k0+=32){
    u16x8 av  = *(const u16x8_a*)(Arow + k0);
    u16x8 bv0 = *(const u16x8_a*)(Brow + k0);
    u16x8 bv1 = *(const u16x8_a*)(Brow + k0 + 8);
    __syncthreads();
    *(u16x8_a*)(a_s + ar*32 + ak)      = av;
    *(u16x8_a*)(b_s + br*32 + bk)      = bv0;
    *(u16x8_a*)(b_s + br*32 + bk + 8)  = bv1;
    __syncthreads();
    bf16x8 af[2], bfr[4];
    #pragma unroll
    for (int i=0;i<2;i++) af[i]  = ldb(a_s + (wm+i*16+lr)*32 + quad*8);
    #pragma unroll
    for (int j=0;j<4;j++) bfr[j] = ldb(b_s + (wn+j*16+lr)*32 + quad*8);
    #pragma unroll
    for (int i=0;i<2;i++)
      #pragma unroll
      for (int j=0;j<4;j++)
        acc[i][j] = __builtin_amdgcn_mfma_f32_16x16x32_bf16(af[i], bfr[j], acc[i][j], 0,0,0);
  }
  #pragma unroll
  for (int j=0;j<4;j++){
    int col = n0 + wn + j*16 + lr;
    float bb = bias[col];
    #pragma unroll
    for (int i=0;i<2;i++){
      int rowb = wm + i*16 + quad*4;
      #pragma unroll
      for (int r=0;r<4;r++)
        out[(size_t)(rowb+r)*768 + col] = f2bf(acc[i][j][r] + bb);
    }
  }
}

// ---------------- 64-key-tile MFMA flash attention, XCD-swizzled ----------------
// ids 0..383: word. xcd=id&7 selects q-chunk group (L2 locality); 64 q/block, no key split,
//   no barriers. ids 384..479: entity, 16 q/block, 4-way key split + merge.
__global__ __launch_bounds__(256) void attn64(
  const unsigned short* __restrict__ Kb,  const unsigned short* __restrict__ VbT,
  const unsigned short* __restrict__ Qw,  const unsigned short* __restrict__ Qwe,
  const unsigned short* __restrict__ Qew, const unsigned short* __restrict__ Qee,
  const float* __restrict__ am,
  float* __restrict__ outw, float* __restrict__ oute)
{
  int id = blockIdx.x;
  int tid = threadIdx.x, w = tid>>6, lane = tid&63, quad = lane>>4, lr = lane&15;
  bool isword = id < 384;
  int h, qrb;
  const unsigned short *Qa, *Qb;
  float* outp;
  if (isword){
    int xcd = id & 7, pos = id >> 3;     // pos in [0,48)
    int wq  = (xcd<<2) | (pos & 3);      // q-chunk in [0,32) -> 64 queries
    h = pos >> 2;
    qrb = wq*64 + w*16;
    Qa = Qw; Qb = Qwe; outp = outw;
  } else {
    int eid = id - 384;
    h = eid % 12;
    qrb = (eid / 12) * 16;
    Qa = Qew; Qb = Qee; outp = oute;
  }

  __shared__ __align__(16) unsigned int p32[4][16*36];  // stride 36 u32: 16B-aligned, 2-way banks
  __shared__ float mrg[3][64][24];                      // entity-merge only

  const unsigned short* qr = Qa + (size_t)(qrb+lr)*768 + h*64 + quad*8;
  bf16x8 qa0 = ldb(qr), qa1 = ldb(qr + 32);
  qr = Qb + (size_t)(qrb+lr)*768 + h*64 + quad*8;
  bf16x8 qb0 = ldb(qr), qb1 = ldb(qr + 32);

  float m_r[4], l_r[4];
  f32x4 o[4];
  #pragma unroll
  for (int r=0;r<4;r++){ m_r[r] = -1e30f; l_r[r] = 0.f; }
  #pragma unroll
  for (int n2=0;n2<4;n2++) for (int r=0;r<4;r++) o[n2][r] = 0.f;

  int lo, nw, cstart, cstep;
  if (isword){
    lo = qrb - 256; if (lo < 0) lo = 0; lo &= ~63;
    int hi = qrb + 272; if (hi > 2048) hi = 2048; hi = (hi + 63) & ~63;
    nw = (hi - lo) >> 6;
    cstart = 0; cstep = 1;
  } else { lo = 0; nw = 32; cstart = w; cstep = 4; }
  int nc = nw + 2;

  unsigned int* p32w = p32[w];

  for (int c = cstart; c < nc; c += cstep){
    bool entp = c >= nw;
    int j0 = entp ? (2048 + (c-nw)*64) : (lo + c*64);

    // 64-key tile: K rows direct from global (B-layout), V cols from VbT (B-layout)
    bf16x8 kf[4][2], vf[4][2];
    const unsigned short* kp = Kb + (size_t)(j0+lr)*768 + h*64 + quad*8;
    #pragma unroll
    for (int t=0;t<4;t++){
      kf[t][0] = ldb(kp + (size_t)t*16*768);
      kf[t][1] = ldb(kp + (size_t)t*16*768 + 32);
    }
    const unsigned short* vp = VbT + (size_t)(h*64 + lr)*2176 + j0 + quad*8;
    #pragma unroll
    for (int n2=0;n2<4;n2++){
      vf[n2][0] = ldb(vp + (size_t)n2*16*2176);
      vf[n2][1] = ldb(vp + (size_t)n2*16*2176 + 32);
    }

    bf16x8 qf0 = entp ? qb0 : qa0;
    bf16x8 qf1 = entp ? qb1 : qa1;
    f32x4 s[4];
    #pragma unroll
    for (int t=0;t<4;t++){
      f32x4 z = {0.f,0.f,0.f,0.f};
      z = __builtin_amdgcn_mfma_f32_16x16x32_bf16(qf0, kf[t][0], z, 0,0,0);
      z = __builtin_amdgcn_mfma_f32_16x16x32_bf16(qf1, kf[t][1], z, 0,0,0);
      s[t] = z;
    }

    float sc[4][4];
    bool wband = isword && !entp;
    #pragma unroll
    for (int t=0;t<4;t++){
      int j = j0 + t*16 + lr;
      float amj  = am[j];
      float addl = amj * LOG2E;
      #pragma unroll
      for (int r=0;r<4;r++){
        float sv = s[t][r];
        if (wband){
          sv += (amj != 0.f) ? NEGV : 0.f;                              // float_mask pre-add
          int i = qrb + quad*4 + r;
          bool ok = ((unsigned)(i - j + 256) <= 512u) && (sv != 0.f);   // band & !=0 quirk
          sv = ok ? sv : NEGV;
        }
        sc[t][r] = sv * (LOG2E*0.125f) + addl;
      }
    }

    #pragma unroll
    for (int r=0;r<4;r++){
      float mx = fmaxf(fmaxf(sc[0][r],sc[1][r]), fmaxf(sc[2][r],sc[3][r]));
      mx = fmaxf(mx, __shfl_xor(mx, 1));
      mx = fmaxf(mx, __shfl_xor(mx, 2));
      mx = fmaxf(mx, __shfl_xor(mx, 4));
      mx = fmaxf(mx, __shfl_xor(mx, 8));
      float mn = fmaxf(m_r[r], mx);
      float alpha = exp2f(m_r[r] - mn);
      m_r[r] = mn;
      float p0 = exp2f(sc[0][r]-mn), p1 = exp2f(sc[1][r]-mn);
      float p2 = exp2f(sc[2][r]-mn), p3 = exp2f(sc[3][r]-mn);
      unsigned short pb0 = f2bf(p0), pb1 = f2bf(p1);
      unsigned short pb2 = f2bf(p2), pb3 = f2bf(p3);
      float rs = (bf2f(pb0) + bf2f(pb1)) + (bf2f(pb2) + bf2f(pb3));
      rs += __shfl_xor(rs,1); rs += __shfl_xor(rs,2);
      rs += __shfl_xor(rs,4); rs += __shfl_xor(rs,8);
      l_r[r] = l_r[r]*alpha + rs;
      int row = quad*4 + r;
      p32w[row*36 + lr]      = (unsigned int)pb0 | ((unsigned int)pb1 << 16);  // keys (lr, 16+lr)
      p32w[row*36 + 16 + lr] = (unsigned int)pb2 | ((unsigned int)pb3 << 16);  // keys (32+lr, 48+lr)
      #pragma unroll
      for (int n2=0;n2<4;n2++) o[n2][r] *= alpha;
    }

    // P (C-layout) -> two A-frags (keys 0..31, 32..63), wave-local LDS round-trip
    const unsigned int* pbp = &p32w[lr*36 + (quad&1)*8];
    u32x4 ra0 = *(const u32x4_a*)pbp;
    u32x4 rb0 = *(const u32x4_a*)(pbp + 4);
    u32x4 ra1 = *(const u32x4_a*)(pbp + 16);
    u32x4 rb1 = *(const u32x4_a*)(pbp + 20);
    unsigned int f0[4], f1[4];
    if (quad < 2){
      f0[0]=(ra0[0]&0xFFFFu)|(ra0[1]<<16); f0[1]=(ra0[2]&0xFFFFu)|(ra0[3]<<16);
      f0[2]=(rb0[0]&0xFFFFu)|(rb0[1]<<16); f0[3]=(rb0[2]&0xFFFFu)|(rb0[3]<<16);
      f1[0]=(ra1[0]&0xFFFFu)|(ra1[1]<<16); f1[1]=(ra1[2]&0xFFFFu)|(ra1[3]<<16);
      f1[2]=(rb1[0]&0xFFFFu)|(rb1[1]<<16); f1[3]=(rb1[2]&0xFFFFu)|(rb1[3]<<16);
    } else {
      f0[0]=(ra0[0]>>16)|(ra0[1]&0xFFFF0000u); f0[1]=(ra0[2]>>16)|(ra0[3]&0xFFFF0000u);
      f0[2]=(rb0[0]>>16)|(rb0[1]&0xFFFF0000u); f0[3]=(rb0[2]>>16)|(rb0[3]&0xFFFF0000u);
      f1[0]=(ra1[0]>>16)|(ra1[1]&0xFFFF0000u); f1[1]=(ra1[2]>>16)|(ra1[3]&0xFFFF0000u);
      f1[2]=(rb1[0]>>16)|(rb1[1]&0xFFFF0000u); f1[3]=(rb1[2]>>16)|(rb1[3]&0xFFFF0000u);
    }
    u32x4 v0v = {f0[0],f0[1],f0[2],f0[3]};
    u32x4 v1v = {f1[0],f1[1],f1[2],f1[3]};
    bf16x8 pf0 = __builtin_bit_cast(bf16x8, v0v);
    bf16x8 pf1 = __builtin_bit_cast(bf16x8, v1v);

    #pragma unroll
    for (int n2=0;n2<4;n2++){
      o[n2] = __builtin_amdgcn_mfma_f32_16x16x32_bf16(pf0, vf[n2][0], o[n2], 0,0,0);
      o[n2] = __builtin_amdgcn_mfma_f32_16x16x32_bf16(pf1, vf[n2][1], o[n2], 0,0,0);
    }
  }

  if (isword){
    // each wave owns its 16 rows -> direct write, no merge
    #pragma unroll
    for (int n2=0;n2<4;n2++)
      #pragma unroll
      for (int r=0;r<4;r++){
        int row = qrb + quad*4 + r;
        outp[(size_t)row*768 + h*64 + n2*16 + lr] = o[n2][r] / l_r[r];
      }
  } else {
    if (w > 0){
      float* my = &mrg[w-1][lane][0];
      #pragma unroll
      for (int r=0;r<4;r++){ my[r] = m_r[r]; my[4+r] = l_r[r]; }
      #pragma unroll
      for (int n2=0;n2<4;n2++)
        #pragma unroll
        for (int r=0;r<4;r++) my[8+n2*4+r] = o[n2][r];
    }
    __syncthreads();
    if (w == 0){
      for (int p=0; p<3; p++){
        const float* pr = &mrg[p][lane][0];
        #pragma unroll
        for (int r=0;r<4;r++){
          float m2 = pr[r], l2 = pr[4+r];
          float M  = fmaxf(m_r[r], m2);
          float e1 = exp2f(m_r[r]-M), e2 = exp2f(m2-M);
          m_r[r] = M;
          l_r[r] = l_r[r]*e1 + l2*e2;
          #pragma unroll
          for (int n2=0;n2<4;n2++)
            o[n2][r] = o[n2][r]*e1 + pr[8+n2*4+r]*e2;
        }
      }
      #pragma unroll
      for (int n2=0;n2<4;n2++)
        #pragma unroll
        for (int r=0;r<4;r++){
          int row = qrb + quad*4 + r;
          outp[(size_t)row*768 + h*64 + n2*16 + lr] = o[n2][r] / l_r[r];
        }
    }
  }
}

extern "C" void kernel_launch(void* const* d_in, const int* in_sizes, int n_in,
                              void* d_out, int out_size, void* d_ws, size_t ws_size,
                              hipStream_t stream) {
  const float* word  = (const float*)d_in[0];
  const float* ent   = (const float*)d_in[1];
  const float* am    = (const float*)d_in[2];
  const float* q_w   = (const float*)d_in[3];
  const float* q_b   = (const float*)d_in[4];
  const float* k_w   = (const float*)d_in[5];
  const float* k_b   = (const float*)d_in[6];
  const float* v_w   = (const float*)d_in[7];
  const float* v_b   = (const float*)d_in[8];
  const float* w2e_w = (const float*)d_in[9];
  const float* w2e_b = (const float*)d_in[10];
  const float* e2w_w = (const float*)d_in[11];
  const float* e2w_b = (const float*)d_in[12];
  const float* e2e_w = (const float*)d_in[13];
  const float* e2e_b = (const float*)d_in[14];

  unsigned short* ws  = (unsigned short*)d_ws;
  unsigned short* wT  = ws;                       // 6*768*768 bf16
  unsigned short* Ab  = wT  + (size_t)6*589824;   // 2176*768 (bf16 word||ent)
  unsigned short* Kb  = Ab  + (size_t)2176*768;
  unsigned short* Vb  = Kb  + (size_t)2176*768;
  unsigned short* Qw  = Vb  + (size_t)2176*768;   // 2048*768
  unsigned short* Qwe = Qw  + (size_t)2048*768;
  unsigned short* Qew = Qwe + (size_t)2048*768;   // 128*768
  unsigned short* Qee = Qew + (size_t)128*768;
  unsigned short* VbT = Qee + (size_t)128*768;    // 768*2176

  float* outw = (float*)d_out;                    // fp32 output
  float* oute = outw + (size_t)2048*768;

  hipLaunchKernelGGL(prep, dim3(24,24,7), dim3(32,8), 0, stream,
                     k_w, v_w, q_w, w2e_w, e2w_w, e2e_w, word, ent, wT, Ab);
  hipLaunchKernelGGL(gemm2, dim3(136,6), dim3(256), 0, stream,
                     Ab, wT, k_b, v_b, q_b, w2e_b, e2w_b, e2e_b,
                     Kb, Vb, Qw, Qwe, Qew, Qee);
  hipLaunchKernelGGL(transpose_v, dim3(68,24), dim3(32,8), 0, stream, Vb, VbT);
  hipLaunchKernelGGL(attn64, dim3(480), dim3(256), 0, stream,
                     Kb, VbT, Qw, Qwe, Qew, Qee, am, outw, oute);
}